// Round 11
// baseline (167.430 us; speedup 1.0000x reference)
//
#include <hip/hip_runtime.h>

// Problem: B=2, S=4096, E=512, H=8, D=64, window 512->513 (HALF=256)
#define S_LEN  4096
#define NH     8
#define DH     64
#define EMB    512
#define HDIM   512
#define HALF_W 256
#define BATCH  2
#define M_ROWS (BATCH * S_LEN)  // 8192

typedef __attribute__((ext_vector_type(8))) short bf16x8;
typedef __attribute__((ext_vector_type(4))) float f32x4;

#define LOG2E 1.44269504088896f

// ---------- bf16 helpers ----------
__device__ __forceinline__ float b2f(unsigned short u) {
    union { unsigned int i; float f; } v; v.i = ((unsigned int)u) << 16; return v.f;
}
__device__ __forceinline__ unsigned short f2b(float f) {
    unsigned int x = __float_as_uint(f);
    unsigned int r = (x + 0x7fffu + ((x >> 16) & 1u)) >> 16;   // RNE
    return (unsigned short)r;
}
// packed bf16 pair, round-half-up (1 ulp vs RNE on ties only)
__device__ __forceinline__ unsigned int f2bpk(float a, float b) {
    return ((__float_as_uint(a) + 0x8000u) >> 16) |
           ((__float_as_uint(b) + 0x8000u) & 0xffff0000u);
}
__device__ __forceinline__ void unpack2(unsigned int u, float* d) {
    d[0] = b2f((unsigned short)(u & 0xffffu));
    d[1] = b2f((unsigned short)(u >> 16));
}
union FragU { uint4 u; bf16x8 f; };
__device__ __forceinline__ bf16x8 ldfrag(const unsigned short* p) {
    FragU x; x.u = *(const uint4*)p; return x.f;
}

// ---------- async global->LDS, 16B per lane (m97 pattern) ----------
__device__ __forceinline__ void async16(const unsigned short* g, unsigned short* l) {
    __builtin_amdgcn_global_load_lds(
        (__attribute__((address_space(1))) void*)const_cast<unsigned short*>(g),
        (__attribute__((address_space(3))) void*)l, 16, 0, 0);
}

// ---------- inline dtype detect (per-block; deterministic, L2-hot 4KB scan) ----------
__device__ __forceinline__ int detect_flag(const unsigned short* __restrict__ xq) {
    __shared__ int s_flag;
    if (threadIdx.x == 0) s_flag = 0;
    __syncthreads();
    uint4 u = *(const uint4*)(xq + threadIdx.x * 8);
    const unsigned short* us = (const unsigned short*)&u;
    int bad = 0;
#pragma unroll
    for (int i = 0; i < 8; ++i) {
        float v = b2f(us[i]);
        if (!(fabsf(v) < 1.0e6f)) bad = 1;
    }
    if (__any(bad) && (threadIdx.x & 63) == 0) atomicOr(&s_flag, 1);
    __syncthreads();
    return s_flag;   // 1 = fp32 inputs, 0 = bf16 inputs
}

// ---------- fused prep: weight transpose->Wt[n][k] bf16  +  input fp32->bf16 ----------
__global__ __launch_bounds__(256) void prep(
    const void* __restrict__ xq, const void* __restrict__ xkv,
    const void* __restrict__ w0, const void* __restrict__ w1,
    const void* __restrict__ w2, const void* __restrict__ w3,
    unsigned short* __restrict__ Wt, unsigned short* __restrict__ Xc)
{
    const int flag = detect_flag((const unsigned short*)xq);
    const int blk = blockIdx.x;
    if (blk < 1024) {
        __shared__ float t[32][33];
        const int z = blk >> 8, idx = blk & 255;
        const void* src = (z == 0) ? w0 : (z == 1) ? w1 : (z == 2) ? w2 : w3;
        unsigned short* dst = Wt + (size_t)z * EMB * EMB;
        const int n0 = (idx & 15) << 5, k0 = (idx >> 4) << 5;
        const int kk = threadIdx.x >> 3;
        const int n4 = (threadIdx.x & 7) << 2;
        if (flag) {
            float4 v = *(const float4*)((const float*)src + (size_t)(k0 + kk) * EMB + n0 + n4);
            t[kk][n4] = v.x; t[kk][n4 + 1] = v.y; t[kk][n4 + 2] = v.z; t[kk][n4 + 3] = v.w;
        } else {
            uint2 u = *(const uint2*)((const unsigned short*)src + (size_t)(k0 + kk) * EMB + n0 + n4);
            unpack2(u.x, &t[kk][n4]); unpack2(u.y, &t[kk][n4 + 2]);
        }
        __syncthreads();
        const int nn = threadIdx.x >> 3;
        const int ks = (threadIdx.x & 7) << 2;
        uint2 pk;
        pk.x = (unsigned int)f2b(t[ks + 0][nn]) | ((unsigned int)f2b(t[ks + 1][nn]) << 16);
        pk.y = (unsigned int)f2b(t[ks + 2][nn]) | ((unsigned int)f2b(t[ks + 3][nn]) << 16);
        *(uint2*)(dst + (size_t)(n0 + nn) * EMB + k0 + ks) = pk;
    } else {
        if (!flag) return;
        const int idx = blk - 1024;
        const int z = idx >> 11;
        const float* src = (const float*)(z ? xkv : xq);
        unsigned short* dst = Xc + (size_t)z * M_ROWS * EMB;
        const size_t base = ((size_t)(idx & 2047) * 256 + threadIdx.x) * 8;
        float4 a = *(const float4*)(src + base);
        float4 b = *(const float4*)(src + base + 4);
        uint4 pk;
        pk.x = (unsigned int)f2b(a.x) | ((unsigned int)f2b(a.y) << 16);
        pk.y = (unsigned int)f2b(a.z) | ((unsigned int)f2b(a.w) << 16);
        pk.z = (unsigned int)f2b(b.x) | ((unsigned int)f2b(b.y) << 16);
        pk.w = (unsigned int)f2b(b.z) | ((unsigned int)f2b(b.w) << 16);
        *(uint4*)(dst + base) = pk;
    }
}

// ---------- GEMM staging issue (one buffer) ----------
__device__ __forceinline__ void gemm_issue(
    const unsigned short* __restrict__ A, const unsigned short* __restrict__ Bt,
    int m0, int k0, unsigned short (*Ab)[64], unsigned short (*Bb)[64],
    int srow, int sp)
{
#pragma unroll
    for (int i = 0; i < 4; ++i) {
        const int row = (i << 5) + srow;
        const int gcol = ((sp ^ (row & 7)) << 3);
        async16(A + (size_t)(m0 + row) * EMB + k0 + gcol, &Ab[row][sp << 3]);
    }
#pragma unroll
    for (int i = 0; i < 2; ++i) {
        const int row = (i << 5) + srow;
        const int gcol = ((sp ^ (row & 7)) << 3);
        async16(Bt + (size_t)row * EMB + k0 + gcol, &Bb[row][sp << 3]);
    }
}

// ---------- MFMA GEMM core v5: 128x64, BK=64, DOUBLE-buffered, 1 barrier/iter ----------
// {sync; issue next->buf^1; compute buf}: loads get a full compute phase in flight
// before the next sync's vmcnt(0) drain.
__device__ __forceinline__ void mgemm_core5(
    const unsigned short* __restrict__ A, const unsigned short* __restrict__ Bt,
    int m0, f32x4 (*acc)[2],
    unsigned short (*A_lds)[128][64], unsigned short (*B_lds)[64][64])
{
    const int tid  = threadIdx.x;
    const int lane = tid & 63;
    const int w    = tid >> 6;
    const int wm   = (w >> 1) << 6;
    const int wn   = (w & 1) << 5;
    const int qcol = lane & 15;
    const int quad = lane >> 4;
    const int srow = tid >> 3;
    const int sp   = tid & 7;

    gemm_issue(A, Bt, m0, 0, A_lds[0], B_lds[0], srow, sp);

    for (int it = 0; it < 8; ++it) {
        __syncthreads();   // drains buf[it&1] loads; protects buf[(it+1)&1] from old reads
        if (it < 7)
            gemm_issue(A, Bt, m0, (it + 1) << 6,
                       A_lds[(it + 1) & 1], B_lds[(it + 1) & 1], srow, sp);
        const int bi = it & 1;
#pragma unroll
        for (int kh = 0; kh < 2; ++kh) {
            bf16x8 af[4], bf[2];
#pragma unroll
            for (int i = 0; i < 4; ++i) {
                const int row = wm + (i << 4) + qcol;
                const int p   = ((kh << 2) + quad) ^ (row & 7);
                af[i] = ldfrag(&A_lds[bi][row][p << 3]);
            }
#pragma unroll
            for (int j = 0; j < 2; ++j) {
                const int row = wn + (j << 4) + qcol;
                const int p   = ((kh << 2) + quad) ^ (row & 7);
                bf[j] = ldfrag(&B_lds[bi][row][p << 3]);
            }
#pragma unroll
            for (int i = 0; i < 4; ++i)
#pragma unroll
                for (int j = 0; j < 2; ++j)
                    acc[i][j] = __builtin_amdgcn_mfma_f32_16x16x32_bf16(af[i], bf[j], acc[i][j], 0, 0, 0);
        }
    }
}

// fused QKV: 1536 blocks; XCD-grouped. Q pre-scaled by 0.125*log2e for attn exp2.
__global__ __launch_bounds__(256) void gemm_qkv(
    const void* __restrict__ xq, const void* __restrict__ xkv,
    const unsigned short* __restrict__ Xc, const unsigned short* __restrict__ Wt,
    unsigned short* __restrict__ Qb, unsigned short* __restrict__ Kb,
    unsigned short* __restrict__ Vtb)
{
    const int flag = detect_flag((const unsigned short*)xq);
    __shared__ __align__(16) unsigned short A_lds[2][128][64];
    __shared__ __align__(16) unsigned short B_lds[2][64][64];
    const int blk = blockIdx.x;
    const int xcd = blk & 7, idx = blk >> 3;
    const int mi = idx / 24, ni = idx - mi * 24;
    const int m0 = ((xcd << 3) + mi) << 7;
    const int n0 = ni << 6;

    const unsigned short* A;
    if (flag) A = Xc + (n0 < 512 ? (size_t)0 : (size_t)M_ROWS * EMB);
    else      A = (const unsigned short*)(n0 < 512 ? xq : xkv);
    const unsigned short* Bt = Wt + (size_t)n0 * EMB;

    f32x4 acc[4][2];
#pragma unroll
    for (int i = 0; i < 4; ++i)
#pragma unroll
        for (int j = 0; j < 2; ++j) acc[i][j] = (f32x4){0.f, 0.f, 0.f, 0.f};

    mgemm_core5(A, Bt, m0, acc, A_lds, B_lds);

    const int lane = threadIdx.x & 63, w = threadIdx.x >> 6;
    const int wm = (w >> 1) << 6, wn = (w & 1) << 5;
    const int qcol = lane & 15, quad = lane >> 4;
    const int mode = n0 >> 9;   // 0=Q, 1=K, 2=V
    const float qscale = 0.125f * LOG2E;
#pragma unroll
    for (int ms = 0; ms < 4; ++ms)
#pragma unroll
        for (int ns = 0; ns < 2; ++ns)
#pragma unroll
            for (int r = 0; r < 4; ++r) {
                const int m = m0 + wm + (ms << 4) + (quad << 2) + r;
                const int n = n0 + wn + (ns << 4) + qcol;
                if (mode == 0) {
                    Qb[(size_t)m * HDIM + n] = f2b(acc[ms][ns][r] * qscale);
                } else if (mode == 1) {
                    Kb[(size_t)m * HDIM + (n - 512)] = f2b(acc[ms][ns][r]);
                } else {
                    const int hd = n - 1024;
                    const int bb = m >> 12, s = m & (S_LEN - 1);
                    const int hh = hd >> 6, d = hd & 63;
                    Vtb[((size_t)((bb * NH + hh) * DH + d)) * S_LEN + s] = f2b(acc[ms][ns][r]);
                }
            }
}

// output projection: 512 blocks; XCD-grouped
__global__ __launch_bounds__(256) void gemm_out(
    const void* __restrict__ xq,
    const unsigned short* __restrict__ A, const unsigned short* __restrict__ Bt,
    void* __restrict__ C)
{
    const int flag = detect_flag((const unsigned short*)xq);
    __shared__ __align__(16) unsigned short A_lds[2][128][64];
    __shared__ __align__(16) unsigned short B_lds[2][64][64];
    const int blk = blockIdx.x;
    const int xcd = blk & 7, idx = blk >> 3;
    const int mi = idx >> 3, ni = idx & 7;
    const int m0 = ((xcd << 3) + mi) << 7;
    const int n0 = ni << 6;

    f32x4 acc[4][2];
#pragma unroll
    for (int i = 0; i < 4; ++i)
#pragma unroll
        for (int j = 0; j < 2; ++j) acc[i][j] = (f32x4){0.f, 0.f, 0.f, 0.f};

    mgemm_core5(A, Bt + (size_t)n0 * EMB, m0, acc, A_lds, B_lds);

    const int lane = threadIdx.x & 63, w = threadIdx.x >> 6;
    const int wm = (w >> 1) << 6, wn = (w & 1) << 5;
    const int qcol = lane & 15, quad = lane >> 4;
#pragma unroll
    for (int ms = 0; ms < 4; ++ms)
#pragma unroll
        for (int ns = 0; ns < 2; ++ns)
#pragma unroll
            for (int r = 0; r < 4; ++r) {
                const int m = m0 + wm + (ms << 4) + (quad << 2) + r;
                const int n = n0 + wn + (ns << 4) + qcol;
                const float v = acc[ms][ns][r];
                if (flag) ((float*)C)[(size_t)m * HDIM + n] = v;
                else      ((unsigned short*)C)[(size_t)m * HDIM + n] = f2b(v);
            }
}

// ---------- attn staging issue (one buffer, chunk j0) ----------
__device__ __forceinline__ void attn_issue(
    const unsigned short* __restrict__ Kg, const unsigned short* __restrict__ Vt,
    int b, int h, int j0,
    unsigned short (*Kb)[64], unsigned short (*Vb)[64], int srow, int sp)
{
#pragma unroll
    for (int i = 0; i < 2; ++i) {
        const int row  = (i << 5) + srow;           // 0..63
        const int gseg = (sp ^ (row & 7)) << 3;
        const int jc = min(max(j0 + row, 0), S_LEN - 1);
        async16(Kg + (size_t)(b * S_LEN + jc) * HDIM + h * DH + gseg, &Kb[row][sp << 3]);
        const int js = min(max(j0 + gseg, 0), S_LEN - 8);
        async16(Vt + ((size_t)((b * NH + h) * DH + row)) * S_LEN + js, &Vb[row][sp << 3]);
    }
}

// ---------- MFMA flash attention v4: dbuf staging, exp2 softmax, masked-chunk skip ----------
// Q pre-scaled by 0.125*log2e => p = exp2(z - slope2*|dd| - 12*log2e).
__global__ __launch_bounds__(256) void attn_mfma(
    const unsigned short* __restrict__ Q,
    const unsigned short* __restrict__ Kg,
    const unsigned short* __restrict__ Vt,
    unsigned short* __restrict__ O)
{
    __shared__ __align__(16) unsigned short K_lds[2][64][64];
    __shared__ __align__(16) unsigned short V_lds[2][64][64];
    __shared__ __align__(16) unsigned short P_lds[4][32][72];

    const int tid  = threadIdx.x;
    const int lane = tid & 63;
    const int w    = tid >> 6;
    const int blk  = blockIdx.x;
    const int bh   = blk >> 5;
    const int r5   = blk & 31;
    const int tile = ((r5 & 7) << 2) | (r5 >> 3);
    const int h    = bh & (NH - 1);
    const int b    = bh >> 3;
    const int t0   = tile << 7;
    const int tq0  = t0 + (w << 5);

    const int qcol = lane & 15;
    const int quad = lane >> 4;
    const float slope2 = LOG2E / (float)(2 << h);   // slope * log2e
    const float bias2  = 12.0f * LOG2E;

    bf16x8 qf[2][2];
#pragma unroll
    for (int qs = 0; qs < 2; ++qs) {
        const unsigned short* qrow =
            Q + (size_t)(b * S_LEN + tq0 + (qs << 4) + qcol) * HDIM + h * DH;
        qf[qs][0] = ldfrag(qrow + quad * 8);
        qf[qs][1] = ldfrag(qrow + 32 + quad * 8);
    }

    f32x4 Oacc[2][4];
#pragma unroll
    for (int qs = 0; qs < 2; ++qs)
#pragma unroll
        for (int i = 0; i < 4; ++i) Oacc[qs][i] = (f32x4){0.f, 0.f, 0.f, 0.f};
    float lsum[2] = {0.f, 0.f};

    const int srow = tid >> 3;
    const int sp   = tid & 7;

    attn_issue(Kg, Vt, b, h, t0 - HALF_W, K_lds[0], V_lds[0], srow, sp);

    for (int c = 0; c < 10; ++c) {
        const int j0 = t0 - HALF_W + (c << 6);
        __syncthreads();
        if (c < 9)
            attn_issue(Kg, Vt, b, h, j0 + 64,
                       K_lds[(c + 1) & 1], V_lds[(c + 1) & 1], srow, sp);
        const int bi = c & 1;

        // wave-uniform: skip chunk fully outside this wave's window
        if (j0 + 63 < tq0 - HALF_W || j0 > tq0 + 31 + HALF_W) continue;

        // S^T + mask/exp2 -> P_lds
#pragma unroll
        for (int qs = 0; qs < 2; ++qs) {
            const int qv = tq0 + (qs << 4) + qcol;
#pragma unroll
            for (int ks = 0; ks < 4; ++ks) {
                const int sj0 = j0 + (ks << 4);
                unsigned short* pdst = &P_lds[w][(qs << 4) + qcol][(ks << 4) + (quad << 2)];
                // wave-uniform: fully-masked 16x16 subtile -> zero P, skip MFMA+exp
                if (sj0 + 15 < tq0 + (qs << 4) - HALF_W ||
                    sj0 > tq0 + (qs << 4) + 15 + HALF_W) {
                    *(uint2*)pdst = (uint2){0u, 0u};
                    continue;
                }
                const int krow = (ks << 4) + qcol;
                const bf16x8 kf0 = ldfrag(&K_lds[bi][krow][(quad ^ (krow & 7)) << 3]);
                const bf16x8 kf1 = ldfrag(&K_lds[bi][krow][((4 + quad) ^ (krow & 7)) << 3]);
                f32x4 z = (f32x4){0.f, 0.f, 0.f, 0.f};
                z = __builtin_amdgcn_mfma_f32_16x16x32_bf16(kf0, qf[qs][0], z, 0, 0, 0);
                z = __builtin_amdgcn_mfma_f32_16x16x32_bf16(kf1, qf[qs][1], z, 0, 0, 0);
                float p[4];
#pragma unroll
                for (int r = 0; r < 4; ++r) {
                    const int j  = sj0 + (quad << 2) + r;
                    const int dd = qv - j;
                    const int ad = dd < 0 ? -dd : dd;
                    const bool ok = (ad <= HALF_W) && ((unsigned)j < (unsigned)S_LEN);
                    const float arg = fmaf(-slope2, (float)ad, z[r] - bias2);
                    const float e = exp2f(arg);
                    p[r] = ok ? e : 0.0f;
                    lsum[qs] += p[r];
                }
                uint2 pk;
                pk.x = f2bpk(p[0], p[1]);
                pk.y = f2bpk(p[2], p[3]);
                *(uint2*)pdst = pk;
            }
        }
        // O^T += V^T P^T
#pragma unroll
        for (int qs = 0; qs < 2; ++qs) {
            const bf16x8 pf0 = ldfrag(&P_lds[w][(qs << 4) + qcol][quad * 8]);
            const bf16x8 pf1 = ldfrag(&P_lds[w][(qs << 4) + qcol][32 + quad * 8]);
#pragma unroll
            for (int ds = 0; ds < 4; ++ds) {
                const int vrow = (ds << 4) + qcol;
                const bf16x8 vf0 = ldfrag(&V_lds[bi][vrow][(quad ^ (vrow & 7)) << 3]);
                const bf16x8 vf1 = ldfrag(&V_lds[bi][vrow][((4 + quad) ^ (vrow & 7)) << 3]);
                Oacc[qs][ds] = __builtin_amdgcn_mfma_f32_16x16x32_bf16(vf0, pf0, Oacc[qs][ds], 0, 0, 0);
                Oacc[qs][ds] = __builtin_amdgcn_mfma_f32_16x16x32_bf16(vf1, pf1, Oacc[qs][ds], 0, 0, 0);
            }
        }
    }

#pragma unroll
    for (int qs = 0; qs < 2; ++qs) {
        float l = lsum[qs];
        l += __shfl_xor(l, 16, 64);
        l += __shfl_xor(l, 32, 64);
        const float rz = 1.0f / l;
        unsigned short* obase =
            O + (size_t)(b * S_LEN + tq0 + (qs << 4) + qcol) * HDIM + h * DH;
#pragma unroll
        for (int ds = 0; ds < 4; ++ds) {
            uint2 pk;
            pk.x = f2bpk(Oacc[qs][ds][0] * rz, Oacc[qs][ds][1] * rz);
            pk.y = f2bpk(Oacc[qs][ds][2] * rz, Oacc[qs][ds][3] * rz);
            *(uint2*)(obase + (ds << 4) + (quad << 2)) = pk;
        }
    }
}

// ---------- launch: 4 kernels ----------
extern "C" void kernel_launch(void* const* d_in, const int* in_sizes, int n_in,
                              void* d_out, int out_size, void* d_ws, size_t ws_size,
                              hipStream_t stream) {
    const void* xq  = d_in[0];
    const void* xkv = d_in[1];
    const void* wq  = d_in[2];
    const void* wk  = d_in[3];
    const void* wv  = d_in[4];
    const void* wo  = d_in[5];

    unsigned short* Qb  = (unsigned short*)((char*)d_ws + 256);
    unsigned short* Kb  = Qb  + (size_t)M_ROWS * HDIM;
    unsigned short* Vtb = Kb  + (size_t)M_ROWS * HDIM;
    unsigned short* Wt  = Vtb + (size_t)M_ROWS * HDIM;
    unsigned short* Wto = Wt + (size_t)3 * EMB * EMB;
    unsigned short* Xc  = (unsigned short*)d_out;   // dead until gemm_out writes it

    prep<<<1024 + 4096, 256, 0, stream>>>(xq, xkv, wq, wk, wv, wo, Wt, Xc);
    gemm_qkv<<<1536, 256, 0, stream>>>(xq, xkv, Xc, Wt, Qb, Kb, Vtb);
    attn_mfma<<<BATCH * NH * (S_LEN / 128), 256, 0, stream>>>(Qb, Kb, Vtb, Qb);
    gemm_out<<<512, 256, 0, stream>>>(xq, Qb, Wto, d_out);
}